// Round 1
// 189.646 us; speedup vs baseline: 1.0169x; 1.0169x over previous
//
#include <hip/hip_runtime.h>
#include <cmath>

typedef short bf16x8 __attribute__((ext_vector_type(8)));
typedef float f32x4 __attribute__((ext_vector_type(4)));
typedef unsigned short us8v __attribute__((ext_vector_type(8)));

#define T_DIM 1024

__device__ __forceinline__ unsigned short rtn_bf16(float f) {
    unsigned u = __float_as_uint(f);
    return (unsigned short)((u + 0x7FFFu + ((u >> 16) & 1u)) >> 16);
}
__device__ __forceinline__ float bf_to_f(unsigned short h) {
    return __uint_as_float(((unsigned)h) << 16);
}
// Truncation-based exact 3-limb split (subtracting a truncation is exact in fp32)
__device__ __forceinline__ void split3(float f, unsigned short& h1,
                                       unsigned short& h2, unsigned short& h3) {
    unsigned u = __float_as_uint(f);
    h1 = (unsigned short)(u >> 16);
    float r1 = f - __uint_as_float(u & 0xFFFF0000u);
    unsigned u1 = __float_as_uint(r1);
    h2 = (unsigned short)(u1 >> 16);
    float r2 = r1 - __uint_as_float(u1 & 0xFFFF0000u);
    h3 = rtn_bf16(r2);
}

// split 8 floats -> 3 limb us8v and store at swizzled LDS offset
__device__ __forceinline__ void split_store8(const float4& a, const float4& b,
                                             unsigned short* __restrict__ A0,
                                             unsigned short* __restrict__ A1,
                                             unsigned short* __restrict__ A2,
                                             int off) {
    const float fv[8] = {a.x, a.y, a.z, a.w, b.x, b.y, b.z, b.w};
    us8v o1, o2, o3;
    #pragma unroll
    for (int i = 0; i < 8; ++i) {
        unsigned short h1, h2, h3;
        split3(fv[i], h1, h2, h3);
        o1[i] = h1; o2[i] = h2; o3[i] = h3;
    }
    *(us8v*)&A0[off] = o1;
    *(us8v*)&A1[off] = o2;
    *(us8v*)&A2[off] = o3;
}

// ---------------------------------------------------------------------------
// Kernel 0: split w (fp32 [k][n]) into 3 bf16 limbs, TRANSPOSED: wT[n][k].
// ---------------------------------------------------------------------------
__global__ __launch_bounds__(256) void lif_wsplit(const float* __restrict__ w,
                                                  unsigned short* __restrict__ wT1,
                                                  unsigned short* __restrict__ wT2,
                                                  unsigned short* __restrict__ wT3) {
    const int id = blockIdx.x * 256 + threadIdx.x;
    const int k = id >> 8, n = id & 255;
    unsigned short h1, h2, h3;
    split3(w[id], h1, h2, h3);
    const int o = n * 256 + k;
    wT1[o] = h1; wT2[o] = h2; wT3[o] = h3;
}

// ---------------------------------------------------------------------------
// Kernel 1: bf16-MFMA GEMM, double-buffered LDS pipeline.
// R8 change vs R7/192us version: 2x LDS buffers (48 KiB), ONE barrier per
// K-step, A-prefetch issued AFTER the barrier so no vmem is in flight at any
// barrier drain (the compiler's vmcnt(0)-before-s_barrier no longer stalls
// on HBM latency). Schedule per iter:
//   ds_read frags(buf cur) -> split avn -> ds_write(buf cur^1) -> barrier
//   -> issue A load(kt+2) -> MFMA phase (B pipelined from L2).
// Hazards: all reads of a buffer precede barrier_kt; the overwrite of that
// buffer happens after barrier_kt in iter kt+1 -> single barrier suffices.
// MFMA order / K order / swizzle / epilogue are IDENTICAL to the previous
// version -> bit-identical output.
// 6 MFMA products: a1w1,a1w2,a2w1,a2w2,a1w3,a3w1.
// Block 128m x 128n, 4 waves each 64x64. grid (512, 2).
// ---------------------------------------------------------------------------
__global__ __launch_bounds__(256) void lif_gemm_mfma(const float* __restrict__ in,
                                                     const unsigned short* __restrict__ wT1,
                                                     const unsigned short* __restrict__ wT2,
                                                     const unsigned short* __restrict__ wT3,
                                                     float* __restrict__ xbuf) {
    __shared__ unsigned short As[2][3][128 * 32];   // 2 buffers x 3 limbs, 48 KiB

    const int tid  = threadIdx.x;
    const int bm   = blockIdx.x;           // 0..511
    const int bn   = blockIdx.y;           // 0..1
    const int wave = tid >> 6;
    const int lane = tid & 63;
    const int l15  = lane & 15;
    const int quad = lane >> 4;
    const int wm   = (wave >> 1) * 64;
    const int wn   = (wave & 1) * 64;

    f32x4 acc[4][4];
    #pragma unroll
    for (int i = 0; i < 4; ++i)
        #pragma unroll
        for (int j = 0; j < 4; ++j) acc[i][j] = (f32x4){0.f, 0.f, 0.f, 0.f};

    const int r  = tid >> 1;               // staging row 0..127
    const int hf = tid & 1;                // staging k-half (16 floats)
    const int rx = r & 3;                  // XOR swizzle key (4 chunks/row)
    const int off0 = r * 32 + (((hf << 1) | 0) ^ rx) * 8;
    const int off1 = r * 32 + (((hf << 1) | 1) ^ rx) * 8;
    const float* arow = in + (size_t)(bm * 128 + r) * 256 + hf * 16;

    // ---- prologue: tile 0 -> buf0; issue tile-1 loads ----
    float4 av0[4];
    #pragma unroll
    for (int j = 0; j < 4; ++j) av0[j] = *(const float4*)(arow + j * 4);
    float4 avn[4];                          // holds data for tile kt+1
    #pragma unroll
    for (int j = 0; j < 4; ++j) avn[j] = *(const float4*)(arow + 32 + j * 4);
    split_store8(av0[0], av0[1], &As[0][0][0], &As[0][1][0], &As[0][2][0], off0);
    split_store8(av0[2], av0[3], &As[0][0][0], &As[0][1][0], &As[0][2][0], off1);
    __syncthreads();

    #pragma unroll
    for (int kt = 0; kt < 8; ++kt) {
        const int cur = kt & 1;

        // 1) A fragments for tile kt (ds_read latency overlaps split VALU below)
        bf16x8 af[3][4];
        #pragma unroll
        for (int mt = 0; mt < 4; ++mt) {
            const int m  = wm + mt * 16 + l15;
            const int ro = m * 32 + ((quad ^ (m & 3)) * 8);
            af[0][mt] = *(const bf16x8*)&As[cur][0][ro];
            af[1][mt] = *(const bf16x8*)&As[cur][1][ro];
            af[2][mt] = *(const bf16x8*)&As[cur][2][ro];
        }

        // 2) split tile kt+1 into the other buffer
        if (kt < 7) {
            split_store8(avn[0], avn[1], &As[cur ^ 1][0][0], &As[cur ^ 1][1][0],
                         &As[cur ^ 1][2][0], off0);
            split_store8(avn[2], avn[3], &As[cur ^ 1][0][0], &As[cur ^ 1][1][0],
                         &As[cur ^ 1][2][0], off1);
        }

        // 3) single barrier: nothing vmem-pending here (A prefetch is issued
        //    after, B loads are consumed within the MFMA phase)
        __syncthreads();

        // 4) prefetch tile kt+2 -> latency hides under the MFMA phase
        if (kt < 6) {
            const float* ap = arow + (kt + 2) * 32;
            #pragma unroll
            for (int j = 0; j < 4; ++j) avn[j] = *(const float4*)(ap + j * 4);
        }

        // 5) MFMA phase (identical order to previous version)
        const int k0 = kt * 32;
        size_t wo = (size_t)(bn * 128 + wn + l15) * 256 + k0 + quad * 8;
        bf16x8 b1 = *(const bf16x8*)(wT1 + wo);
        bf16x8 b2 = *(const bf16x8*)(wT2 + wo);
        bf16x8 b3 = *(const bf16x8*)(wT3 + wo);

        #pragma unroll
        for (int nt = 0; nt < 4; ++nt) {
            bf16x8 n1, n2, n3;
            if (nt < 3) {
                const size_t won = wo + (size_t)16 * 256;   // next ncol = +16
                n1 = *(const bf16x8*)(wT1 + won);
                n2 = *(const bf16x8*)(wT2 + won);
                n3 = *(const bf16x8*)(wT3 + won);
            }
            #pragma unroll
            for (int mt = 0; mt < 4; ++mt) {
                f32x4 a = acc[mt][nt];
                a = __builtin_amdgcn_mfma_f32_16x16x32_bf16(af[0][mt], b1, a, 0, 0, 0);
                a = __builtin_amdgcn_mfma_f32_16x16x32_bf16(af[0][mt], b2, a, 0, 0, 0);
                a = __builtin_amdgcn_mfma_f32_16x16x32_bf16(af[1][mt], b1, a, 0, 0, 0);
                a = __builtin_amdgcn_mfma_f32_16x16x32_bf16(af[1][mt], b2, a, 0, 0, 0);
                a = __builtin_amdgcn_mfma_f32_16x16x32_bf16(af[0][mt], b3, a, 0, 0, 0);
                a = __builtin_amdgcn_mfma_f32_16x16x32_bf16(af[2][mt], b1, a, 0, 0, 0);
                acc[mt][nt] = a;
            }
            if (nt < 3) { b1 = n1; b2 = n2; b3 = n3; wo += (size_t)16 * 256; }
        }
    }

    // epilogue: C/D layout col=lane&15, row=quad*4+reg
    #pragma unroll
    for (int mt = 0; mt < 4; ++mt) {
        #pragma unroll
        for (int nt = 0; nt < 4; ++nt) {
            const int C  = bn * 128 + wn + nt * 16 + l15;
            const int Rb = bm * 128 + wm + mt * 16 + quad * 4;
            #pragma unroll
            for (int reg = 0; reg < 4; ++reg)
                xbuf[(size_t)(Rb + reg) * 256 + C] = acc[mt][nt][reg];
        }
    }
}

// ---------------------------------------------------------------------------
// Kernel 2: LIF scan. One thread per (b,o), fp64 state. 256 blocks x 64 thr.
// __launch_bounds__(64, 1): full VGPR budget so the ping-pong buffers stay in
// registers. R8 change: batch depth 32 -> 64 (64 loads / ~1280 cy of compute
// cover per batch vs ~640 before -> HBM/L3 latency fully hidden), and U
// stores are nontemporal (write-only stream, skip cache retention).
// Math identical -> bit-identical output.
// ---------------------------------------------------------------------------
__global__ __launch_bounds__(64, 1) void lif_scan(const float* __restrict__ xbuf,
                                                  float* __restrict__ U,
                                                  double dcy_syn, double dcy_mem,
                                                  double scl_mem) {
    const int b = blockIdx.x >> 2;
    const int o = (blockIdx.x & 3) * 64 + threadIdx.x;

    const float* xp = xbuf + (size_t)b * T_DIM * 256 + o;
    float* up = U + (size_t)b * T_DIM * 256 + o;

    up[0] = 0.0f;                          // U[b][0][o] = initial state
    double syn = 0.0, mem = 0.0;

    float bufA[64], bufB[64];
    #pragma unroll
    for (int j = 0; j < 64; ++j)
        bufA[j] = __builtin_nontemporal_load(xp + (size_t)j * 256);

    #pragma unroll 1
    for (int bt = 0; bt < 8; ++bt) {       // 8 x (2 batches of 64) = 1024 steps
        const int tb = bt * 128;
        // phase A: prefetch next batch into B, consume A
        {
            const float* np = xp + (size_t)(tb + 64) * 256;
            #pragma unroll
            for (int j = 0; j < 64; ++j)
                bufB[j] = __builtin_nontemporal_load(np + (size_t)j * 256);
        }
        #pragma unroll
        for (int j = 0; j < 64; ++j) {
            const int t = tb + j;
            double nm = dcy_mem * mem + scl_mem * syn;
            if (mem - 1.0 > 0.0) nm = 0.0;
            syn = dcy_syn * syn + (double)bufA[j];
            mem = nm;
            __builtin_nontemporal_store((float)mem, up + (size_t)(t + 1) * 256);
        }
        // phase B: prefetch next batch into A (guard last), consume B
        if (bt < 7) {
            const float* np = xp + (size_t)(tb + 128) * 256;
            #pragma unroll
            for (int j = 0; j < 64; ++j)
                bufA[j] = __builtin_nontemporal_load(np + (size_t)j * 256);
        }
        #pragma unroll
        for (int j = 0; j < 64; ++j) {
            const int t = tb + 64 + j;
            double nm = dcy_mem * mem + scl_mem * syn;
            if (mem - 1.0 > 0.0) nm = 0.0;
            syn = dcy_syn * syn + (double)bufB[j];
            mem = nm;
            if (t < T_DIM - 1)             // skip only the final t=1023 store
                __builtin_nontemporal_store((float)mem, up + (size_t)(t + 1) * 256);
        }
    }
}

extern "C" void kernel_launch(void* const* d_in, const int* in_sizes, int n_in,
                              void* d_out, int out_size, void* d_ws, size_t ws_size,
                              hipStream_t stream) {
    const float* in = (const float*)d_in[0];   // fp32 [64][1024][256]
    const float* w  = (const float*)d_in[1];   // fp32 [256][256]
    float* U = (float*)d_out;                  // fp32 [64][1024][256]

    const double dcy_mem = exp(-0.001 / (0.01  + 1e-16));
    const double dcy_syn = exp(-0.001 / (0.005 + 1e-16));
    const double scl_mem = 1.0 - dcy_mem;

    // ws layout: wT1|wT2|wT3 (3 x 128 KiB bf16) | xbuf (64 MiB fp32)
    char* ws = (char*)d_ws;
    unsigned short* wT1 = (unsigned short*)ws;
    unsigned short* wT2 = (unsigned short*)(ws + 131072);
    unsigned short* wT3 = (unsigned short*)(ws + 262144);
    float* xbuf = (float*)(ws + 524288);

    lif_wsplit<<<dim3(256), dim3(256), 0, stream>>>(w, wT1, wT2, wT3);
    lif_gemm_mfma<<<dim3(512, 2), dim3(256), 0, stream>>>(in, wT1, wT2, wT3, xbuf);
    lif_scan<<<dim3(256), dim3(64), 0, stream>>>(xbuf, U, dcy_syn, dcy_mem, scl_mem);
}